// Round 16
// baseline (159.594 us; speedup 1.0000x reference)
//
#include <hip/hip_runtime.h>

#define D 64
#define NBMAX 512   // max buckets (N <= 131072)
#define CAP 4096    // fixed per-bucket capacity in padded binned/csr (mean 2560, +30 sigma)

typedef __attribute__((ext_vector_type(8))) short bf16x8;
typedef __attribute__((ext_vector_type(4))) float f32x4;
typedef __attribute__((ext_vector_type(2))) float f32x2;

__device__ __forceinline__ unsigned short f2bf(float x) {
    union { float f; unsigned u; } v; v.f = x;
    unsigned r = v.u + 0x7fff + ((v.u >> 16) & 1);  // RNE
    return (unsigned short)(r >> 16);
}
__device__ __forceinline__ float bf2f_lo(unsigned u) { return __uint_as_float(u << 16); }
__device__ __forceinline__ float bf2f_hi(unsigned u) { return __uint_as_float(u & 0xffff0000u); }

// ================= fp32 -> bf16 convert (x once) + zero bucketCursor =================
__global__ void f2b_kernel(const float* __restrict__ in, unsigned short* __restrict__ out, int n4,
                           int* __restrict__ bucketCursor, int NB) {
    int i = blockIdx.x * blockDim.x + threadIdx.x;
    if (i < NB) bucketCursor[i] = 0;
    int stride = gridDim.x * blockDim.x;
    for (int j = i; j < n4; j += stride) {
        float4 v = ((const float4*)in)[j];
        ushort4 o;
        o.x = f2bf(v.x); o.y = f2bf(v.y); o.z = f2bf(v.z); o.w = f2bf(v.w);
        ((ushort4*)out)[j] = o;
    }
}

// ================= weight prep: pack Wcat = [Wl^T ; Wr^T] into per-lane MFMA A-fragments =================
__global__ void wprep_kernel(const float* __restrict__ Wl, const float* __restrict__ Wr,
                             unsigned short* __restrict__ wbuf) {
    int layer = blockIdx.x >> 4;
    int f = blockIdx.x & 15;
    int ot = f >> 2, ks = f & 3;
    int l = threadIdx.x;  // 64
    const float* W = (ks < 2 ? Wl : Wr) + (size_t)layer * D * D;
    const float* srcp = W + (size_t)(ot * 16 + (l & 15)) * D + (ks & 1) * 32 + (l >> 4) * 8;
    float4 w0 = *(const float4*)srcp;
    float4 w1 = *(const float4*)(srcp + 4);
    unsigned short* dstp = wbuf + (((size_t)layer * 16 + f) * 64 + l) * 8;
    dstp[0] = f2bf(w0.x); dstp[1] = f2bf(w0.y); dstp[2] = f2bf(w0.z); dstp[3] = f2bf(w0.w);
    dstp[4] = f2bf(w1.x); dstp[5] = f2bf(w1.y); dstp[6] = f2bf(w1.z); dstp[7] = f2bf(w1.w);
}

// ================= CSR build: fixed-capacity buckets (r14-validated; no global scan) =================
// bucket = dst >> 8; bucket b owns binned/csr[b*CAP .. b*CAP+CAP).
// binned entry (UNSIGNED): (dstLocal << 24) | src   (r7 lesson: unsigned unpack)

__global__ __launch_bounds__(256) void bin_scatter(const int* __restrict__ src,
                                                   const int* __restrict__ dst,
                                                   int* __restrict__ bucketCursor,
                                                   unsigned* __restrict__ binned, int E, int NB) {
    __shared__ int hst[NBMAX];
    int t = threadIdx.x;
    for (int i = t; i < NBMAX; i += 256) hst[i] = 0;
    __syncthreads();
    int per = (E + gridDim.x - 1) / gridDim.x;
    int beg = blockIdx.x * per;
    int end = min(E, beg + per);
    int ed[8];
#pragma unroll 8
    for (int k = 0; k < 8; ++k) {
        int e = beg + t + k * 256;
        if (e < end) {
            int d = dst[e];
            ed[k] = d;
            atomicAdd(&hst[d >> 8], 1);
        } else ed[k] = -1;
    }
    __syncthreads();
    for (int i = t; i < NB; i += 256) {
        int c = hst[i];
        if (c) hst[i] = atomicAdd(&bucketCursor[i], c);  // reserve contiguous run in bucket i
    }
    __syncthreads();
#pragma unroll 8
    for (int k = 0; k < 8; ++k) {
        int e = beg + t + k * 256;
        if (e < end) {
            int d = ed[k];
            int pos = atomicAdd(&hst[d >> 8], 1);
            if (pos < CAP)  // overflow guard (never hit: mean 2560, +30 sigma)
                binned[(size_t)(d >> 8) * CAP + pos] = (unsigned)src[e] | ((unsigned)(d & 255) << 24);
        }
    }
}

// one block per bucket: exact per-node CSR in LDS, coalesced flush; writes rowStart+rowDeg.
// r16: also counting-sorts its 256 nodes by degree (64-bin LDS sort) -> perm[], so
// aggregate octets (8 consecutive perm entries) have near-uniform degree (md ~= deg).
__global__ __launch_bounds__(256) void csr_local(const unsigned* __restrict__ binned,
                                                 const int* __restrict__ bucketCursor,
                                                 int* __restrict__ rowStart, int* __restrict__ rowDeg,
                                                 int* __restrict__ perm,
                                                 int* __restrict__ csr, int N, int NB) {
    __shared__ int lcount[256];
    __shared__ int sbuf[256];
    __shared__ int ccur[256];
    __shared__ int buf[CAP];
    __shared__ int dhist[64];
    __shared__ int dscan[64];
    int t = threadIdx.x;
    int b = blockIdx.x;
    int nodeBase = b << 8;
    int nNodes = min(256, N - nodeBase);
    int base = b * CAP;
    int cnt = min(bucketCursor[b], CAP);

    lcount[t] = 0;
    if (t < 64) dhist[t] = 0;
    __syncthreads();
    for (int i = t; i < cnt; i += 256) atomicAdd(&lcount[binned[base + i] >> 24], 1);
    __syncthreads();
    int v = lcount[t];
    sbuf[t] = v;
    __syncthreads();
    for (int d = 1; d < 256; d <<= 1) {
        int add = (t >= d) ? sbuf[t - d] : 0;
        __syncthreads();
        sbuf[t] += add;
        __syncthreads();
    }
    int excl = sbuf[t] - v;
    ccur[t] = excl;
    if (t < nNodes) { rowStart[nodeBase + t] = base + excl; rowDeg[nodeBase + t] = v; }

    // ---- degree counting-sort of this bucket's nodes -> perm ----
    int bin = min(v, 63);
    int lpos = 0;
    if (t < nNodes) lpos = atomicAdd(&dhist[bin], 1);
    __syncthreads();
    if (t < 64) {  // exclusive scan of 64 bins (64 threads, LDS reads)
        int s = 0;
        for (int i = 0; i < t; ++i) s += dhist[i];
        dscan[t] = s;
    }
    __syncthreads();
    if (t < nNodes) perm[nodeBase + dscan[bin] + lpos] = nodeBase + t;
    __syncthreads();

    // ---- CSR scatter + coalesced flush ----
    for (int i = t; i < cnt; i += 256) {
        unsigned u = binned[base + i];
        int pos = atomicAdd(&ccur[u >> 24], 1);
        buf[pos] = (int)(u & 0x00FFFFFFu);
    }
    __syncthreads();
    for (int i = t; i < cnt; i += 256) csr[base + i] = buf[i];  // coalesced
}

// ================= aggregate (bf16 in / bf16 out, fp32 accumulate) =================
// r13 structure (proven): one node per 8-lane group, grid-stride 2048 blocks,
// predicated accumulate, ci=0 pad, wave-uniform iteration count (r9 lesson),
// packed f32x2 accumulators. r16: node = perm[idx] (degree-sorted octets ->
// md ~= deg, ~40% fewer padded batches). agg writes still 128B/row coalesced.
__global__ __launch_bounds__(256) void aggregate_bf16(
    const unsigned short* __restrict__ h, const int* __restrict__ rowStart,
    const int* __restrict__ rowDeg, const int* __restrict__ csr,
    const int* __restrict__ perm,
    unsigned short* __restrict__ agg, int N) {
    int wid  = (blockIdx.x * blockDim.x + threadIdx.x) >> 6;
    int lane = threadIdx.x & 63;
    int nw   = (gridDim.x * blockDim.x) >> 6;
    int g = lane >> 3;       // group = node within octet
    int o = lane & 7;        // 16B chunk / index-preload slot
    int gbase = lane & 56;   // group base lane
    int nOct = (N + 7) >> 3;
    for (int n8 = wid; n8 < nOct; n8 += nw) {
        int idx = (n8 << 3) + g;
        bool valid = idx < N;
        int node = 0, beg = 0, deg = 0;
        if (valid) {
            node = perm[idx];
            beg = rowStart[node];
            deg = rowDeg[node];
        }
        int md = deg;  // wave-max degree (uniform; near-deg thanks to sort)
        md = max(md, __shfl_xor(md, 8));
        md = max(md, __shfl_xor(md, 16));
        md = max(md, __shfl_xor(md, 32));
        f32x2 a01 = {0.f, 0.f}, a23 = a01, a45 = a01, a67 = a01;
        int ci = (o < deg) ? csr[beg + o] : 0;  // converged load; 0 for pad lanes
        for (int mb = 0; mb < md; mb += 8) {
            int ciN = 0;  // prefetch next batch's indices under this batch's gathers
            if (mb + 8 < md) ciN = (mb + 8 + o < deg) ? csr[beg + mb + 8 + o] : 0;
#pragma unroll
            for (int mm = 0; mm < 8; ++mm) {
                int m = mb + mm;
                int s = __shfl(ci, gbase | mm);  // all 64 lanes active (md uniform)
                uint4 v = *(const uint4*)(h + (size_t)s * D + o * 8);
                if (m < deg) {                   // predicate accumulate only
                    f32x2 t0 = {bf2f_lo(v.x), bf2f_hi(v.x)};
                    f32x2 t1 = {bf2f_lo(v.y), bf2f_hi(v.y)};
                    f32x2 t2 = {bf2f_lo(v.z), bf2f_hi(v.z)};
                    f32x2 t3 = {bf2f_lo(v.w), bf2f_hi(v.w)};
                    a01 += t0; a23 += t1; a45 += t2; a67 += t3;  // v_pk_add_f32
                }
            }
            ci = ciN;
        }
        if (valid) {  // lane owns its 16B chunk; group writes node's full 128B row
            float inv = 1.0f / fmaxf((float)deg, 1.0f);
            uint4 ov;
            ov.x = (unsigned)f2bf(a01.x * inv) | ((unsigned)f2bf(a01.y * inv) << 16);
            ov.y = (unsigned)f2bf(a23.x * inv) | ((unsigned)f2bf(a23.y * inv) << 16);
            ov.z = (unsigned)f2bf(a45.x * inv) | ((unsigned)f2bf(a45.y * inv) << 16);
            ov.w = (unsigned)f2bf(a67.x * inv) | ((unsigned)f2bf(a67.y * inv) << 16);
            *(uint4*)(agg + (size_t)node * D + o * 8) = ov;
        }
    }
}

// ================= transform via MFMA (+ optional fused classifier) =================
// out[N,64] = relu?( [agg|h][N,128] @ Wcat[128,64] + bl );  CLS: out2[N,2] = h3 @ Wout^T + bout
// D frag: row index = lane&15, feature = ot*16 + (lane>>4)*4 + j   (verified r6)
// Separate kernel from aggregate ON PURPOSE: fusing strangles the gather's TLP
// (r4: VGPR remat; r14: occupancy 15.7% + LDS conflicts; both ~+20us/layer).
template <bool RELU, bool CLS>
__global__ __launch_bounds__(256) void transform_mfma(
    const unsigned short* __restrict__ agg, const unsigned short* __restrict__ h,
    const unsigned short* __restrict__ wbuf, const float* __restrict__ bl,
    const float* __restrict__ Wout, const float* __restrict__ bout,
    unsigned short* __restrict__ out, float* __restrict__ out2, int N) {
    int t = threadIdx.x;
    int lane = t & 63;
    int w = t >> 6;
    int rq = lane & 15;
    int kg = lane >> 4;

    bf16x8 wf[16];
#pragma unroll
    for (int f = 0; f < 16; ++f)
        wf[f] = *(const bf16x8*)(wbuf + ((size_t)f * 64 + lane) * 8);
    float4 bias[4];
#pragma unroll
    for (int ot = 0; ot < 4; ++ot)
        bias[ot] = *(const float4*)(bl + ot * 16 + kg * 4);
    float4 wo0[4], wo1[4];
    float b0 = 0.f, b1 = 0.f;
    if (CLS) {
#pragma unroll
        for (int ot = 0; ot < 4; ++ot) {
            wo0[ot] = *(const float4*)(Wout + ot * 16 + kg * 4);
            wo1[ot] = *(const float4*)(Wout + D + ot * 16 + kg * 4);
        }
        b0 = bout[0]; b1 = bout[1];
    }

    int tiles = (N + 15) >> 4;
    for (int tile = blockIdx.x * 4 + w; tile < tiles; tile += gridDim.x * 4) {
        int r = tile * 16 + rq;
        int rc = min(r, N - 1);
        const unsigned short* ar = agg + (size_t)rc * D;
        const unsigned short* hr = h + (size_t)rc * D;
        bf16x8 d0 = *(const bf16x8*)(ar + kg * 8);
        bf16x8 d1 = *(const bf16x8*)(ar + 32 + kg * 8);
        bf16x8 d2 = *(const bf16x8*)(hr + kg * 8);
        bf16x8 d3 = *(const bf16x8*)(hr + 32 + kg * 8);

        f32x4 acc0 = {0.f, 0.f, 0.f, 0.f}, acc1 = acc0, acc2 = acc0, acc3 = acc0;
        acc0 = __builtin_amdgcn_mfma_f32_16x16x32_bf16(wf[0],  d0, acc0, 0, 0, 0);
        acc0 = __builtin_amdgcn_mfma_f32_16x16x32_bf16(wf[1],  d1, acc0, 0, 0, 0);
        acc0 = __builtin_amdgcn_mfma_f32_16x16x32_bf16(wf[2],  d2, acc0, 0, 0, 0);
        acc0 = __builtin_amdgcn_mfma_f32_16x16x32_bf16(wf[3],  d3, acc0, 0, 0, 0);
        acc1 = __builtin_amdgcn_mfma_f32_16x16x32_bf16(wf[4],  d0, acc1, 0, 0, 0);
        acc1 = __builtin_amdgcn_mfma_f32_16x16x32_bf16(wf[5],  d1, acc1, 0, 0, 0);
        acc1 = __builtin_amdgcn_mfma_f32_16x16x32_bf16(wf[6],  d2, acc1, 0, 0, 0);
        acc1 = __builtin_amdgcn_mfma_f32_16x16x32_bf16(wf[7],  d3, acc1, 0, 0, 0);
        acc2 = __builtin_amdgcn_mfma_f32_16x16x32_bf16(wf[8],  d0, acc2, 0, 0, 0);
        acc2 = __builtin_amdgcn_mfma_f32_16x16x32_bf16(wf[9],  d1, acc2, 0, 0, 0);
        acc2 = __builtin_amdgcn_mfma_f32_16x16x32_bf16(wf[10], d2, acc2, 0, 0, 0);
        acc2 = __builtin_amdgcn_mfma_f32_16x16x32_bf16(wf[11], d3, acc2, 0, 0, 0);
        acc3 = __builtin_amdgcn_mfma_f32_16x16x32_bf16(wf[12], d0, acc3, 0, 0, 0);
        acc3 = __builtin_amdgcn_mfma_f32_16x16x32_bf16(wf[13], d1, acc3, 0, 0, 0);
        acc3 = __builtin_amdgcn_mfma_f32_16x16x32_bf16(wf[14], d2, acc3, 0, 0, 0);
        acc3 = __builtin_amdgcn_mfma_f32_16x16x32_bf16(wf[15], d3, acc3, 0, 0, 0);

        f32x4 av[4] = {acc0, acc1, acc2, acc3};
        if (CLS) {
            float p0 = 0.f, p1 = 0.f;
#pragma unroll
            for (int ot = 0; ot < 4; ++ot) {
                float x0 = av[ot][0] + bias[ot].x;
                float x1 = av[ot][1] + bias[ot].y;
                float x2 = av[ot][2] + bias[ot].z;
                float x3 = av[ot][3] + bias[ot].w;
                p0 += x0 * wo0[ot].x + x1 * wo0[ot].y + x2 * wo0[ot].z + x3 * wo0[ot].w;
                p1 += x0 * wo1[ot].x + x1 * wo1[ot].y + x2 * wo1[ot].z + x3 * wo1[ot].w;
            }
            p0 += __shfl_xor(p0, 16); p1 += __shfl_xor(p1, 16);
            p0 += __shfl_xor(p0, 32); p1 += __shfl_xor(p1, 32);
            if (kg == 0 && r < N) {
                out2[(size_t)r * 2 + 0] = p0 + b0;
                out2[(size_t)r * 2 + 1] = p1 + b1;
            }
        } else if (r < N) {
            unsigned short* orow = out + (size_t)r * D + kg * 4;
#pragma unroll
            for (int ot = 0; ot < 4; ++ot) {
                float x0 = av[ot][0] + bias[ot].x;
                float x1 = av[ot][1] + bias[ot].y;
                float x2 = av[ot][2] + bias[ot].z;
                float x3 = av[ot][3] + bias[ot].w;
                if (RELU) {
                    x0 = fmaxf(x0, 0.f); x1 = fmaxf(x1, 0.f);
                    x2 = fmaxf(x2, 0.f); x3 = fmaxf(x3, 0.f);
                }
                uint2 o;
                o.x = (unsigned)f2bf(x0) | ((unsigned)f2bf(x1) << 16);
                o.y = (unsigned)f2bf(x2) | ((unsigned)f2bf(x3) << 16);
                *(uint2*)(orow + ot * 16) = o;
            }
        }
    }
}

extern "C" void kernel_launch(void* const* d_in, const int* in_sizes, int n_in,
                              void* d_out, int out_size, void* d_ws, size_t ws_size,
                              hipStream_t stream) {
    const float* x    = (const float*)d_in[0];
    const int*   ei   = (const int*)d_in[1];
    const float* Wl   = (const float*)d_in[2];
    const float* bl   = (const float*)d_in[3];
    const float* Wr   = (const float*)d_in[4];
    const float* Wout = (const float*)d_in[5];
    const float* bout = (const float*)d_in[6];
    float*       out  = (float*)d_out;

    const int N = in_sizes[0] / D;
    const int E = in_sizes[1] / 2;
    const int* src = ei;
    const int* dst = ei + E;
    const int NB = (N + 255) >> 8;  // <= NBMAX

    char* ws = (char*)d_ws;
    size_t off = 0;
    auto alloc = [&](size_t bytes) {
        char* p = ws + off;
        off = (off + bytes + 255) & ~(size_t)255;
        return p;
    };
    int*            bucketCursor = (int*)alloc((size_t)NB * 4);
    int*            rowStart     = (int*)alloc((size_t)N * 4);
    int*            rowDeg       = (int*)alloc((size_t)N * 4);
    int*            perm         = (int*)alloc((size_t)N * 4);
    int*            csr          = (int*)alloc((size_t)NB * CAP * 4);
    unsigned short* xb           = (unsigned short*)alloc((size_t)N * D * 2);
    unsigned short* hA           = (unsigned short*)alloc((size_t)N * D * 2);
    unsigned short* hB           = (unsigned short*)alloc((size_t)N * D * 2);
    unsigned short* aggB         = (unsigned short*)alloc((size_t)N * D * 2);
    unsigned short* wbuf         = (unsigned short*)alloc((size_t)3 * 16 * 64 * 8 * 2);
    // binned (NB*CAP*4 = 6.4MB) aliases hB (12.8MB): dead after csr_local, hB first written in layer 2
    unsigned*       binned       = (unsigned*)hB;

    // ---- prep (f2b zeroes bucketCursor -> no hipMemsetAsync anywhere) ----
    f2b_kernel<<<2048, 256, 0, stream>>>(x, xb, N * D / 4, bucketCursor, NB);
    wprep_kernel<<<48, 64, 0, stream>>>(Wl, Wr, wbuf);

    // ---- CSR build (2 kernels; fixed-capacity buckets + per-bucket degree sort) ----
    bin_scatter<<<512, 256, 0, stream>>>(src, dst, bucketCursor, binned, E, NB);
    csr_local<<<NB, 256, 0, stream>>>(binned, bucketCursor, rowStart, rowDeg, perm, csr, N, NB);

    const int WFRAG = 16 * 64 * 8;  // per-layer wbuf stride (ushorts)

    // ---- 3 layers (split kernels; grid-stride, proven r13 grids) ----
    aggregate_bf16<<<2048, 256, 0, stream>>>(xb, rowStart, rowDeg, csr, perm, aggB, N);
    transform_mfma<true, false><<<1024, 256, 0, stream>>>(
        aggB, xb, wbuf, bl, nullptr, nullptr, hA, nullptr, N);

    aggregate_bf16<<<2048, 256, 0, stream>>>(hA, rowStart, rowDeg, csr, perm, aggB, N);
    transform_mfma<true, false><<<1024, 256, 0, stream>>>(
        aggB, hA, wbuf + WFRAG, bl + D, nullptr, nullptr, hB, nullptr, N);

    aggregate_bf16<<<2048, 256, 0, stream>>>(hB, rowStart, rowDeg, csr, perm, aggB, N);
    transform_mfma<false, true><<<1024, 256, 0, stream>>>(
        aggB, hB, wbuf + 2 * WFRAG, bl + 2 * D, Wout, bout, nullptr, out, N);
}

// Round 17
// 130.195 us; speedup vs baseline: 1.2258x; 1.2258x over previous
//
#include <hip/hip_runtime.h>

#define D 64
#define NBMAX 512   // max buckets (N <= 131072)
#define CAP 4096    // fixed per-bucket capacity in padded binned/csr (mean 2560, +30 sigma)

typedef __attribute__((ext_vector_type(8))) short bf16x8;
typedef __attribute__((ext_vector_type(4))) float f32x4;
typedef __attribute__((ext_vector_type(2))) float f32x2;

__device__ __forceinline__ unsigned short f2bf(float x) {
    union { float f; unsigned u; } v; v.f = x;
    unsigned r = v.u + 0x7fff + ((v.u >> 16) & 1);  // RNE
    return (unsigned short)(r >> 16);
}
__device__ __forceinline__ float bf2f_lo(unsigned u) { return __uint_as_float(u << 16); }
__device__ __forceinline__ float bf2f_hi(unsigned u) { return __uint_as_float(u & 0xffff0000u); }

// ================= fp32 -> bf16 convert (x once) + zero bucketCursor =================
__global__ void f2b_kernel(const float* __restrict__ in, unsigned short* __restrict__ out, int n4,
                           int* __restrict__ bucketCursor, int NB) {
    int i = blockIdx.x * blockDim.x + threadIdx.x;
    if (i < NB) bucketCursor[i] = 0;
    int stride = gridDim.x * blockDim.x;
    for (int j = i; j < n4; j += stride) {
        float4 v = ((const float4*)in)[j];
        ushort4 o;
        o.x = f2bf(v.x); o.y = f2bf(v.y); o.z = f2bf(v.z); o.w = f2bf(v.w);
        ((ushort4*)out)[j] = o;
    }
}

// ================= weight prep: pack Wcat = [Wl^T ; Wr^T] into per-lane MFMA A-fragments =================
__global__ void wprep_kernel(const float* __restrict__ Wl, const float* __restrict__ Wr,
                             unsigned short* __restrict__ wbuf) {
    int layer = blockIdx.x >> 4;
    int f = blockIdx.x & 15;
    int ot = f >> 2, ks = f & 3;
    int l = threadIdx.x;  // 64
    const float* W = (ks < 2 ? Wl : Wr) + (size_t)layer * D * D;
    const float* srcp = W + (size_t)(ot * 16 + (l & 15)) * D + (ks & 1) * 32 + (l >> 4) * 8;
    float4 w0 = *(const float4*)srcp;
    float4 w1 = *(const float4*)(srcp + 4);
    unsigned short* dstp = wbuf + (((size_t)layer * 16 + f) * 64 + l) * 8;
    dstp[0] = f2bf(w0.x); dstp[1] = f2bf(w0.y); dstp[2] = f2bf(w0.z); dstp[3] = f2bf(w0.w);
    dstp[4] = f2bf(w1.x); dstp[5] = f2bf(w1.y); dstp[6] = f2bf(w1.z); dstp[7] = f2bf(w1.w);
}

// ================= CSR build: fixed-capacity buckets (r14-validated; no global scan) =================
// bucket = dst >> 8; bucket b owns binned/csr[b*CAP .. b*CAP+CAP).
// binned entry (UNSIGNED): (dstLocal << 24) | src   (r7 lesson: unsigned unpack)

__global__ __launch_bounds__(256) void bin_scatter(const int* __restrict__ src,
                                                   const int* __restrict__ dst,
                                                   int* __restrict__ bucketCursor,
                                                   unsigned* __restrict__ binned, int E, int NB) {
    __shared__ int hst[NBMAX];
    int t = threadIdx.x;
    for (int i = t; i < NBMAX; i += 256) hst[i] = 0;
    __syncthreads();
    int per = (E + gridDim.x - 1) / gridDim.x;
    int beg = blockIdx.x * per;
    int end = min(E, beg + per);
    int ed[8];
#pragma unroll 8
    for (int k = 0; k < 8; ++k) {
        int e = beg + t + k * 256;
        if (e < end) {
            int d = dst[e];
            ed[k] = d;
            atomicAdd(&hst[d >> 8], 1);
        } else ed[k] = -1;
    }
    __syncthreads();
    for (int i = t; i < NB; i += 256) {
        int c = hst[i];
        if (c) hst[i] = atomicAdd(&bucketCursor[i], c);  // reserve contiguous run in bucket i
    }
    __syncthreads();
#pragma unroll 8
    for (int k = 0; k < 8; ++k) {
        int e = beg + t + k * 256;
        if (e < end) {
            int d = ed[k];
            int pos = atomicAdd(&hst[d >> 8], 1);
            if (pos < CAP)  // overflow guard (never hit: mean 2560, +30 sigma)
                binned[(size_t)(d >> 8) * CAP + pos] = (unsigned)src[e] | ((unsigned)(d & 255) << 24);
        }
    }
}

// one block per bucket: exact per-node CSR in LDS, coalesced flush; writes rowStart+rowDeg.
__global__ __launch_bounds__(256) void csr_local(const unsigned* __restrict__ binned,
                                                 const int* __restrict__ bucketCursor,
                                                 int* __restrict__ rowStart, int* __restrict__ rowDeg,
                                                 int* __restrict__ csr, int N, int NB) {
    __shared__ int lcount[256];
    __shared__ int sbuf[256];
    __shared__ int ccur[256];
    __shared__ int buf[CAP];
    int t = threadIdx.x;
    int b = blockIdx.x;
    int nodeBase = b << 8;
    int nNodes = min(256, N - nodeBase);
    int base = b * CAP;
    int cnt = min(bucketCursor[b], CAP);

    lcount[t] = 0;
    __syncthreads();
    for (int i = t; i < cnt; i += 256) atomicAdd(&lcount[binned[base + i] >> 24], 1);
    __syncthreads();
    int v = lcount[t];
    sbuf[t] = v;
    __syncthreads();
    for (int d = 1; d < 256; d <<= 1) {
        int add = (t >= d) ? sbuf[t - d] : 0;
        __syncthreads();
        sbuf[t] += add;
        __syncthreads();
    }
    int excl = sbuf[t] - v;
    ccur[t] = excl;
    if (t < nNodes) { rowStart[nodeBase + t] = base + excl; rowDeg[nodeBase + t] = v; }
    __syncthreads();

    for (int i = t; i < cnt; i += 256) {
        unsigned u = binned[base + i];
        int pos = atomicAdd(&ccur[u >> 24], 1);
        buf[pos] = (int)(u & 0x00FFFFFFu);
    }
    __syncthreads();
    for (int i = t; i < cnt; i += 256) csr[base + i] = buf[i];  // coalesced
}

// ================= aggregate (bf16 in / bf16 out, fp32 accumulate) =================
// r13/r15 structure (143.7us proven): one node per 8-lane group, grid-stride 2048
// blocks, natural node order (r16: perm indirection regressed -15us), predicated
// accumulate, ci=0 pad, wave-uniform iteration count (r9 shfl-source lesson).
// r17: EXPLICIT 8-deep load batching — all 8 shfls, then all 8 uint4 loads into
// NAMED variables (live simultaneously -> compiler must keep 8 gathers in flight;
// r10 profile showed VGPR=20, i.e. it had serialized the pipeline to ~2), then
// the 8 predicated accumulates.
#define ACC8(vv)                                      \
    {                                                 \
        f32x2 t0 = {bf2f_lo(vv.x), bf2f_hi(vv.x)};    \
        f32x2 t1 = {bf2f_lo(vv.y), bf2f_hi(vv.y)};    \
        f32x2 t2 = {bf2f_lo(vv.z), bf2f_hi(vv.z)};    \
        f32x2 t3 = {bf2f_lo(vv.w), bf2f_hi(vv.w)};    \
        a01 += t0; a23 += t1; a45 += t2; a67 += t3;   \
    }

__global__ __launch_bounds__(256) void aggregate_bf16(
    const unsigned short* __restrict__ h, const int* __restrict__ rowStart,
    const int* __restrict__ rowDeg, const int* __restrict__ csr,
    unsigned short* __restrict__ agg, int N) {
    int wid  = (blockIdx.x * blockDim.x + threadIdx.x) >> 6;
    int lane = threadIdx.x & 63;
    int nw   = (gridDim.x * blockDim.x) >> 6;
    int g = lane >> 3;       // group = node within octet
    int o = lane & 7;        // 16B chunk / index-preload slot
    int gbase = lane & 56;   // group base lane
    const unsigned short* hq = h + o * 8;  // lane's fixed 16B column offset
    int nOct = (N + 7) >> 3;
    for (int n8 = wid; n8 < nOct; n8 += nw) {
        int node = (n8 << 3) + g;
        bool valid = node < N;
        int beg = 0, deg = 0;
        if (valid) { beg = rowStart[node]; deg = rowDeg[node]; }
        int md = deg;  // wave-max degree (uniform; group bits are lane bits 3..5)
        md = max(md, __shfl_xor(md, 8));
        md = max(md, __shfl_xor(md, 16));
        md = max(md, __shfl_xor(md, 32));
        f32x2 a01 = {0.f, 0.f}, a23 = a01, a45 = a01, a67 = a01;
        int ci = (o < deg) ? csr[beg + o] : 0;  // converged load; 0 for pad lanes
        for (int mb = 0; mb < md; mb += 8) {
            int ciN = 0;  // prefetch next batch's indices under this batch's gathers
            if (mb + 8 < md) ciN = (mb + 8 + o < deg) ? csr[beg + mb + 8 + o] : 0;
            // phase 1: all 8 index broadcasts (all 64 lanes active; md uniform)
            int s0 = __shfl(ci, gbase | 0), s1 = __shfl(ci, gbase | 1);
            int s2 = __shfl(ci, gbase | 2), s3 = __shfl(ci, gbase | 3);
            int s4 = __shfl(ci, gbase | 4), s5 = __shfl(ci, gbase | 5);
            int s6 = __shfl(ci, gbase | 6), s7 = __shfl(ci, gbase | 7);
            // phase 2: all 8 gathers issued back-to-back (named -> all live -> in flight)
            uint4 v0 = *(const uint4*)(hq + (size_t)s0 * D);
            uint4 v1 = *(const uint4*)(hq + (size_t)s1 * D);
            uint4 v2 = *(const uint4*)(hq + (size_t)s2 * D);
            uint4 v3 = *(const uint4*)(hq + (size_t)s3 * D);
            uint4 v4 = *(const uint4*)(hq + (size_t)s4 * D);
            uint4 v5 = *(const uint4*)(hq + (size_t)s5 * D);
            uint4 v6 = *(const uint4*)(hq + (size_t)s6 * D);
            uint4 v7 = *(const uint4*)(hq + (size_t)s7 * D);
            // phase 3: predicated accumulates (v_pk_add_f32)
            if (mb + 0 < deg) ACC8(v0);
            if (mb + 1 < deg) ACC8(v1);
            if (mb + 2 < deg) ACC8(v2);
            if (mb + 3 < deg) ACC8(v3);
            if (mb + 4 < deg) ACC8(v4);
            if (mb + 5 < deg) ACC8(v5);
            if (mb + 6 < deg) ACC8(v6);
            if (mb + 7 < deg) ACC8(v7);
            ci = ciN;
        }
        if (valid) {  // lane owns its 16B chunk exclusively; no reduction
            float inv = 1.0f / fmaxf((float)deg, 1.0f);
            uint4 ov;
            ov.x = (unsigned)f2bf(a01.x * inv) | ((unsigned)f2bf(a01.y * inv) << 16);
            ov.y = (unsigned)f2bf(a23.x * inv) | ((unsigned)f2bf(a23.y * inv) << 16);
            ov.z = (unsigned)f2bf(a45.x * inv) | ((unsigned)f2bf(a45.y * inv) << 16);
            ov.w = (unsigned)f2bf(a67.x * inv) | ((unsigned)f2bf(a67.y * inv) << 16);
            *(uint4*)(agg + (size_t)node * D + o * 8) = ov;
        }
    }
}

// ================= transform via MFMA (+ optional fused classifier) =================
// out[N,64] = relu?( [agg|h][N,128] @ Wcat[128,64] + bl );  CLS: out2[N,2] = h3 @ Wout^T + bout
// D frag: row index = lane&15, feature = ot*16 + (lane>>4)*4 + j   (verified r6)
// Separate kernel from aggregate ON PURPOSE: fusing strangles the gather's TLP
// (r4: VGPR remat; r14: occupancy 15.7% + LDS conflicts; both ~+20us/layer).
template <bool RELU, bool CLS>
__global__ __launch_bounds__(256) void transform_mfma(
    const unsigned short* __restrict__ agg, const unsigned short* __restrict__ h,
    const unsigned short* __restrict__ wbuf, const float* __restrict__ bl,
    const float* __restrict__ Wout, const float* __restrict__ bout,
    unsigned short* __restrict__ out, float* __restrict__ out2, int N) {
    int t = threadIdx.x;
    int lane = t & 63;
    int w = t >> 6;
    int rq = lane & 15;
    int kg = lane >> 4;

    bf16x8 wf[16];
#pragma unroll
    for (int f = 0; f < 16; ++f)
        wf[f] = *(const bf16x8*)(wbuf + ((size_t)f * 64 + lane) * 8);
    float4 bias[4];
#pragma unroll
    for (int ot = 0; ot < 4; ++ot)
        bias[ot] = *(const float4*)(bl + ot * 16 + kg * 4);
    float4 wo0[4], wo1[4];
    float b0 = 0.f, b1 = 0.f;
    if (CLS) {
#pragma unroll
        for (int ot = 0; ot < 4; ++ot) {
            wo0[ot] = *(const float4*)(Wout + ot * 16 + kg * 4);
            wo1[ot] = *(const float4*)(Wout + D + ot * 16 + kg * 4);
        }
        b0 = bout[0]; b1 = bout[1];
    }

    int tiles = (N + 15) >> 4;
    for (int tile = blockIdx.x * 4 + w; tile < tiles; tile += gridDim.x * 4) {
        int r = tile * 16 + rq;
        int rc = min(r, N - 1);
        const unsigned short* ar = agg + (size_t)rc * D;
        const unsigned short* hr = h + (size_t)rc * D;
        bf16x8 d0 = *(const bf16x8*)(ar + kg * 8);
        bf16x8 d1 = *(const bf16x8*)(ar + 32 + kg * 8);
        bf16x8 d2 = *(const bf16x8*)(hr + kg * 8);
        bf16x8 d3 = *(const bf16x8*)(hr + 32 + kg * 8);

        f32x4 acc0 = {0.f, 0.f, 0.f, 0.f}, acc1 = acc0, acc2 = acc0, acc3 = acc0;
        acc0 = __builtin_amdgcn_mfma_f32_16x16x32_bf16(wf[0],  d0, acc0, 0, 0, 0);
        acc0 = __builtin_amdgcn_mfma_f32_16x16x32_bf16(wf[1],  d1, acc0, 0, 0, 0);
        acc0 = __builtin_amdgcn_mfma_f32_16x16x32_bf16(wf[2],  d2, acc0, 0, 0, 0);
        acc0 = __builtin_amdgcn_mfma_f32_16x16x32_bf16(wf[3],  d3, acc0, 0, 0, 0);
        acc1 = __builtin_amdgcn_mfma_f32_16x16x32_bf16(wf[4],  d0, acc1, 0, 0, 0);
        acc1 = __builtin_amdgcn_mfma_f32_16x16x32_bf16(wf[5],  d1, acc1, 0, 0, 0);
        acc1 = __builtin_amdgcn_mfma_f32_16x16x32_bf16(wf[6],  d2, acc1, 0, 0, 0);
        acc1 = __builtin_amdgcn_mfma_f32_16x16x32_bf16(wf[7],  d3, acc1, 0, 0, 0);
        acc2 = __builtin_amdgcn_mfma_f32_16x16x32_bf16(wf[8],  d0, acc2, 0, 0, 0);
        acc2 = __builtin_amdgcn_mfma_f32_16x16x32_bf16(wf[9],  d1, acc2, 0, 0, 0);
        acc2 = __builtin_amdgcn_mfma_f32_16x16x32_bf16(wf[10], d2, acc2, 0, 0, 0);
        acc2 = __builtin_amdgcn_mfma_f32_16x16x32_bf16(wf[11], d3, acc2, 0, 0, 0);
        acc3 = __builtin_amdgcn_mfma_f32_16x16x32_bf16(wf[12], d0, acc3, 0, 0, 0);
        acc3 = __builtin_amdgcn_mfma_f32_16x16x32_bf16(wf[13], d1, acc3, 0, 0, 0);
        acc3 = __builtin_amdgcn_mfma_f32_16x16x32_bf16(wf[14], d2, acc3, 0, 0, 0);
        acc3 = __builtin_amdgcn_mfma_f32_16x16x32_bf16(wf[15], d3, acc3, 0, 0, 0);

        f32x4 av[4] = {acc0, acc1, acc2, acc3};
        if (CLS) {
            float p0 = 0.f, p1 = 0.f;
#pragma unroll
            for (int ot = 0; ot < 4; ++ot) {
                float x0 = av[ot][0] + bias[ot].x;
                float x1 = av[ot][1] + bias[ot].y;
                float x2 = av[ot][2] + bias[ot].z;
                float x3 = av[ot][3] + bias[ot].w;
                p0 += x0 * wo0[ot].x + x1 * wo0[ot].y + x2 * wo0[ot].z + x3 * wo0[ot].w;
                p1 += x0 * wo1[ot].x + x1 * wo1[ot].y + x2 * wo1[ot].z + x3 * wo1[ot].w;
            }
            p0 += __shfl_xor(p0, 16); p1 += __shfl_xor(p1, 16);
            p0 += __shfl_xor(p0, 32); p1 += __shfl_xor(p1, 32);
            if (kg == 0 && r < N) {
                out2[(size_t)r * 2 + 0] = p0 + b0;
                out2[(size_t)r * 2 + 1] = p1 + b1;
            }
        } else if (r < N) {
            unsigned short* orow = out + (size_t)r * D + kg * 4;
#pragma unroll
            for (int ot = 0; ot < 4; ++ot) {
                float x0 = av[ot][0] + bias[ot].x;
                float x1 = av[ot][1] + bias[ot].y;
                float x2 = av[ot][2] + bias[ot].z;
                float x3 = av[ot][3] + bias[ot].w;
                if (RELU) {
                    x0 = fmaxf(x0, 0.f); x1 = fmaxf(x1, 0.f);
                    x2 = fmaxf(x2, 0.f); x3 = fmaxf(x3, 0.f);
                }
                uint2 o;
                o.x = (unsigned)f2bf(x0) | ((unsigned)f2bf(x1) << 16);
                o.y = (unsigned)f2bf(x2) | ((unsigned)f2bf(x3) << 16);
                *(uint2*)(orow + ot * 16) = o;
            }
        }
    }
}

extern "C" void kernel_launch(void* const* d_in, const int* in_sizes, int n_in,
                              void* d_out, int out_size, void* d_ws, size_t ws_size,
                              hipStream_t stream) {
    const float* x    = (const float*)d_in[0];
    const int*   ei   = (const int*)d_in[1];
    const float* Wl   = (const float*)d_in[2];
    const float* bl   = (const float*)d_in[3];
    const float* Wr   = (const float*)d_in[4];
    const float* Wout = (const float*)d_in[5];
    const float* bout = (const float*)d_in[6];
    float*       out  = (float*)d_out;

    const int N = in_sizes[0] / D;
    const int E = in_sizes[1] / 2;
    const int* src = ei;
    const int* dst = ei + E;
    const int NB = (N + 255) >> 8;  // <= NBMAX

    char* ws = (char*)d_ws;
    size_t off = 0;
    auto alloc = [&](size_t bytes) {
        char* p = ws + off;
        off = (off + bytes + 255) & ~(size_t)255;
        return p;
    };
    int*            bucketCursor = (int*)alloc((size_t)NB * 4);
    int*            rowStart     = (int*)alloc((size_t)N * 4);
    int*            rowDeg       = (int*)alloc((size_t)N * 4);
    int*            csr          = (int*)alloc((size_t)NB * CAP * 4);
    unsigned short* xb           = (unsigned short*)alloc((size_t)N * D * 2);
    unsigned short* hA           = (unsigned short*)alloc((size_t)N * D * 2);
    unsigned short* hB           = (unsigned short*)alloc((size_t)N * D * 2);
    unsigned short* aggB         = (unsigned short*)alloc((size_t)N * D * 2);
    unsigned short* wbuf         = (unsigned short*)alloc((size_t)3 * 16 * 64 * 8 * 2);
    // binned (NB*CAP*4 = 6.4MB) aliases hB (12.8MB): dead after csr_local, hB first written in layer 2
    unsigned*       binned       = (unsigned*)hB;

    // ---- prep (f2b zeroes bucketCursor -> no hipMemsetAsync anywhere) ----
    f2b_kernel<<<2048, 256, 0, stream>>>(x, xb, N * D / 4, bucketCursor, NB);
    wprep_kernel<<<48, 64, 0, stream>>>(Wl, Wr, wbuf);

    // ---- CSR build (2 kernels; fixed-capacity buckets, no global scan) ----
    bin_scatter<<<512, 256, 0, stream>>>(src, dst, bucketCursor, binned, E, NB);
    csr_local<<<NB, 256, 0, stream>>>(binned, bucketCursor, rowStart, rowDeg, csr, N, NB);

    const int WFRAG = 16 * 64 * 8;  // per-layer wbuf stride (ushorts)

    // ---- 3 layers (split kernels; grid-stride, proven r13 grids) ----
    aggregate_bf16<<<2048, 256, 0, stream>>>(xb, rowStart, rowDeg, csr, aggB, N);
    transform_mfma<true, false><<<1024, 256, 0, stream>>>(
        aggB, xb, wbuf, bl, nullptr, nullptr, hA, nullptr, N);

    aggregate_bf16<<<2048, 256, 0, stream>>>(hA, rowStart, rowDeg, csr, aggB, N);
    transform_mfma<true, false><<<1024, 256, 0, stream>>>(
        aggB, hA, wbuf + WFRAG, bl + D, nullptr, nullptr, hB, nullptr, N);

    aggregate_bf16<<<2048, 256, 0, stream>>>(hB, rowStart, rowDeg, csr, aggB, N);
    transform_mfma<false, true><<<1024, 256, 0, stream>>>(
        aggB, hB, wbuf + 2 * WFRAG, bl + 2 * D, Wout, bout, nullptr, out, N);
}

// Round 18
// 130.173 us; speedup vs baseline: 1.2260x; 1.0002x over previous
//
#include <hip/hip_runtime.h>

#define D 64
#define NBMAX 512   // max buckets (N <= 131072)
#define CAP 4096    // fixed per-bucket capacity in padded binned/csr (mean 2560, +30 sigma)

typedef __attribute__((ext_vector_type(8))) short bf16x8;
typedef __attribute__((ext_vector_type(4))) float f32x4;
typedef __attribute__((ext_vector_type(2))) float f32x2;

__device__ __forceinline__ unsigned short f2bf(float x) {
    union { float f; unsigned u; } v; v.f = x;
    unsigned r = v.u + 0x7fff + ((v.u >> 16) & 1);  // RNE
    return (unsigned short)(r >> 16);
}
__device__ __forceinline__ float bf2f_lo(unsigned u) { return __uint_as_float(u << 16); }
__device__ __forceinline__ float bf2f_hi(unsigned u) { return __uint_as_float(u & 0xffff0000u); }

// ================= fp32 -> bf16 convert (x once) + zero bucketCursor =================
__global__ void f2b_kernel(const float* __restrict__ in, unsigned short* __restrict__ out, int n4,
                           int* __restrict__ bucketCursor, int NB) {
    int i = blockIdx.x * blockDim.x + threadIdx.x;
    if (i < NB) bucketCursor[i] = 0;
    int stride = gridDim.x * blockDim.x;
    for (int j = i; j < n4; j += stride) {
        float4 v = ((const float4*)in)[j];
        ushort4 o;
        o.x = f2bf(v.x); o.y = f2bf(v.y); o.z = f2bf(v.z); o.w = f2bf(v.w);
        ((ushort4*)out)[j] = o;
    }
}

// ================= weight prep: pack Wcat = [Wl^T ; Wr^T] into per-lane MFMA A-fragments =================
__global__ void wprep_kernel(const float* __restrict__ Wl, const float* __restrict__ Wr,
                             unsigned short* __restrict__ wbuf) {
    int layer = blockIdx.x >> 4;
    int f = blockIdx.x & 15;
    int ot = f >> 2, ks = f & 3;
    int l = threadIdx.x;  // 64
    const float* W = (ks < 2 ? Wl : Wr) + (size_t)layer * D * D;
    const float* srcp = W + (size_t)(ot * 16 + (l & 15)) * D + (ks & 1) * 32 + (l >> 4) * 8;
    float4 w0 = *(const float4*)srcp;
    float4 w1 = *(const float4*)(srcp + 4);
    unsigned short* dstp = wbuf + (((size_t)layer * 16 + f) * 64 + l) * 8;
    dstp[0] = f2bf(w0.x); dstp[1] = f2bf(w0.y); dstp[2] = f2bf(w0.z); dstp[3] = f2bf(w0.w);
    dstp[4] = f2bf(w1.x); dstp[5] = f2bf(w1.y); dstp[6] = f2bf(w1.z); dstp[7] = f2bf(w1.w);
}

// ================= CSR build: fixed-capacity buckets (r14-validated; no global scan) =================
// bucket = dst >> 8; bucket b owns binned/csr[b*CAP .. b*CAP+CAP).
// binned entry (UNSIGNED): (dstLocal << 24) | src   (r7 lesson: unsigned unpack)

__global__ __launch_bounds__(256) void bin_scatter(const int* __restrict__ src,
                                                   const int* __restrict__ dst,
                                                   int* __restrict__ bucketCursor,
                                                   unsigned* __restrict__ binned, int E, int NB) {
    __shared__ int hst[NBMAX];
    int t = threadIdx.x;
    for (int i = t; i < NBMAX; i += 256) hst[i] = 0;
    __syncthreads();
    int per = (E + gridDim.x - 1) / gridDim.x;
    int beg = blockIdx.x * per;
    int end = min(E, beg + per);
    int ed[8];
#pragma unroll 8
    for (int k = 0; k < 8; ++k) {
        int e = beg + t + k * 256;
        if (e < end) {
            int d = dst[e];
            ed[k] = d;
            atomicAdd(&hst[d >> 8], 1);
        } else ed[k] = -1;
    }
    __syncthreads();
    for (int i = t; i < NB; i += 256) {
        int c = hst[i];
        if (c) hst[i] = atomicAdd(&bucketCursor[i], c);  // reserve contiguous run in bucket i
    }
    __syncthreads();
#pragma unroll 8
    for (int k = 0; k < 8; ++k) {
        int e = beg + t + k * 256;
        if (e < end) {
            int d = ed[k];
            int pos = atomicAdd(&hst[d >> 8], 1);
            if (pos < CAP)  // overflow guard (never hit: mean 2560, +30 sigma)
                binned[(size_t)(d >> 8) * CAP + pos] = (unsigned)src[e] | ((unsigned)(d & 255) << 24);
        }
    }
}

// one block per bucket: exact per-node CSR in LDS, coalesced flush; writes rowStart+rowDeg.
__global__ __launch_bounds__(256) void csr_local(const unsigned* __restrict__ binned,
                                                 const int* __restrict__ bucketCursor,
                                                 int* __restrict__ rowStart, int* __restrict__ rowDeg,
                                                 int* __restrict__ csr, int N, int NB) {
    __shared__ int lcount[256];
    __shared__ int sbuf[256];
    __shared__ int ccur[256];
    __shared__ int buf[CAP];
    int t = threadIdx.x;
    int b = blockIdx.x;
    int nodeBase = b << 8;
    int nNodes = min(256, N - nodeBase);
    int base = b * CAP;
    int cnt = min(bucketCursor[b], CAP);

    lcount[t] = 0;
    __syncthreads();
    for (int i = t; i < cnt; i += 256) atomicAdd(&lcount[binned[base + i] >> 24], 1);
    __syncthreads();
    int v = lcount[t];
    sbuf[t] = v;
    __syncthreads();
    for (int d = 1; d < 256; d <<= 1) {
        int add = (t >= d) ? sbuf[t - d] : 0;
        __syncthreads();
        sbuf[t] += add;
        __syncthreads();
    }
    int excl = sbuf[t] - v;
    ccur[t] = excl;
    if (t < nNodes) { rowStart[nodeBase + t] = base + excl; rowDeg[nodeBase + t] = v; }
    __syncthreads();

    for (int i = t; i < cnt; i += 256) {
        unsigned u = binned[base + i];
        int pos = atomicAdd(&ccur[u >> 24], 1);
        buf[pos] = (int)(u & 0x00FFFFFFu);
    }
    __syncthreads();
    for (int i = t; i < cnt; i += 256) csr[base + i] = buf[i];  // coalesced
}

// ================= aggregate (bf16 in / bf16 out, fp32 accumulate) =================
// r17 base (130us proven) + r18: 2-deep cross-batch pipeline. Indices for the
// first 3 batches preloaded up front (ciA/B/C, covers md<=24 ~95% of octets);
// batch m+1's 8 loads issue BEFORE batch m's accumulates -> up to 16 gathers in
// flight per wave and no csr-load on the critical path. md>24 tail = serial form.
// All md branches wave-uniform (r9 shfl-source rule preserved).
#define ACC8(vv)                                      \
    {                                                 \
        f32x2 t0 = {bf2f_lo(vv.x), bf2f_hi(vv.x)};    \
        f32x2 t1 = {bf2f_lo(vv.y), bf2f_hi(vv.y)};    \
        f32x2 t2 = {bf2f_lo(vv.z), bf2f_hi(vv.z)};    \
        f32x2 t3 = {bf2f_lo(vv.w), bf2f_hi(vv.w)};    \
        a01 += t0; a23 += t1; a45 += t2; a67 += t3;   \
    }

#define SHFL8(ci)                                                          \
    s0 = __shfl(ci, gbase | 0); s1 = __shfl(ci, gbase | 1);                \
    s2 = __shfl(ci, gbase | 2); s3 = __shfl(ci, gbase | 3);                \
    s4 = __shfl(ci, gbase | 4); s5 = __shfl(ci, gbase | 5);                \
    s6 = __shfl(ci, gbase | 6); s7 = __shfl(ci, gbase | 7);

#define LOAD8(dst0,dst1,dst2,dst3,dst4,dst5,dst6,dst7)                     \
    dst0 = *(const uint4*)(hq + (size_t)s0 * D);                           \
    dst1 = *(const uint4*)(hq + (size_t)s1 * D);                           \
    dst2 = *(const uint4*)(hq + (size_t)s2 * D);                           \
    dst3 = *(const uint4*)(hq + (size_t)s3 * D);                           \
    dst4 = *(const uint4*)(hq + (size_t)s4 * D);                           \
    dst5 = *(const uint4*)(hq + (size_t)s5 * D);                           \
    dst6 = *(const uint4*)(hq + (size_t)s6 * D);                           \
    dst7 = *(const uint4*)(hq + (size_t)s7 * D);

#define ACC8X(base, v0_,v1_,v2_,v3_,v4_,v5_,v6_,v7_)                       \
    if (base + 0 < deg) ACC8(v0_); if (base + 1 < deg) ACC8(v1_);          \
    if (base + 2 < deg) ACC8(v2_); if (base + 3 < deg) ACC8(v3_);          \
    if (base + 4 < deg) ACC8(v4_); if (base + 5 < deg) ACC8(v5_);          \
    if (base + 6 < deg) ACC8(v6_); if (base + 7 < deg) ACC8(v7_);

__global__ __launch_bounds__(256) void aggregate_bf16(
    const unsigned short* __restrict__ h, const int* __restrict__ rowStart,
    const int* __restrict__ rowDeg, const int* __restrict__ csr,
    unsigned short* __restrict__ agg, int N) {
    int wid  = (blockIdx.x * blockDim.x + threadIdx.x) >> 6;
    int lane = threadIdx.x & 63;
    int nw   = (gridDim.x * blockDim.x) >> 6;
    int g = lane >> 3;       // group = node within octet
    int o = lane & 7;        // 16B chunk / index-preload slot
    int gbase = lane & 56;   // group base lane
    const unsigned short* hq = h + o * 8;  // lane's fixed 16B column offset
    int nOct = (N + 7) >> 3;
    for (int n8 = wid; n8 < nOct; n8 += nw) {
        int node = (n8 << 3) + g;
        bool valid = node < N;
        int beg = 0, deg = 0;
        if (valid) { beg = rowStart[node]; deg = rowDeg[node]; }
        int md = deg;  // wave-max degree (uniform; group bits are lane bits 3..5)
        md = max(md, __shfl_xor(md, 8));
        md = max(md, __shfl_xor(md, 16));
        md = max(md, __shfl_xor(md, 32));
        f32x2 a01 = {0.f, 0.f}, a23 = a01, a45 = a01, a67 = a01;
        // preload indices for first 3 batches (per-lane ?:, no divergent branch)
        int ciA = (o < deg) ? csr[beg + o] : 0;
        int ciB = (8 + o < deg) ? csr[beg + 8 + o] : 0;
        int ciC = (16 + o < deg) ? csr[beg + 16 + o] : 0;
        int s0, s1, s2, s3, s4, s5, s6, s7;
        uint4 v0, v1, v2, v3, v4, v5, v6, v7;
        uint4 w0, w1, w2, w3, w4, w5, w6, w7;
        // batch 0: issue loads
        SHFL8(ciA);
        LOAD8(v0, v1, v2, v3, v4, v5, v6, v7);
        if (md > 8) {  // batch 1 loads issued BEFORE batch 0 accumulates
            SHFL8(ciB);
            LOAD8(w0, w1, w2, w3, w4, w5, w6, w7);
        }
        ACC8X(0, v0, v1, v2, v3, v4, v5, v6, v7);
        if (md > 8) {
            if (md > 16) {  // batch 2 loads issued before batch 1 accumulates
                SHFL8(ciC);
                LOAD8(v0, v1, v2, v3, v4, v5, v6, v7);
            }
            ACC8X(8, w0, w1, w2, w3, w4, w5, w6, w7);
            if (md > 16) {
                ACC8X(16, v0, v1, v2, v3, v4, v5, v6, v7);
            }
        }
        // rare tail (md > 24): serial per-batch form
        for (int mb = 24; mb < md; mb += 8) {
            int ciD = (mb + o < deg) ? csr[beg + mb + o] : 0;
            SHFL8(ciD);
            LOAD8(v0, v1, v2, v3, v4, v5, v6, v7);
            ACC8X(mb, v0, v1, v2, v3, v4, v5, v6, v7);
        }
        if (valid) {  // lane owns its 16B chunk exclusively; no reduction
            float inv = 1.0f / fmaxf((float)deg, 1.0f);
            uint4 ov;
            ov.x = (unsigned)f2bf(a01.x * inv) | ((unsigned)f2bf(a01.y * inv) << 16);
            ov.y = (unsigned)f2bf(a23.x * inv) | ((unsigned)f2bf(a23.y * inv) << 16);
            ov.z = (unsigned)f2bf(a45.x * inv) | ((unsigned)f2bf(a45.y * inv) << 16);
            ov.w = (unsigned)f2bf(a67.x * inv) | ((unsigned)f2bf(a67.y * inv) << 16);
            *(uint4*)(agg + (size_t)node * D + o * 8) = ov;
        }
    }
}

// ================= transform via MFMA (+ optional fused classifier) =================
// out[N,64] = relu?( [agg|h][N,128] @ Wcat[128,64] + bl );  CLS: out2[N,2] = h3 @ Wout^T + bout
// D frag: row index = lane&15, feature = ot*16 + (lane>>4)*4 + j   (verified r6)
// Separate kernel from aggregate ON PURPOSE: fusing strangles the gather's TLP
// (r4: VGPR remat; r14: occupancy 15.7% + LDS conflicts; both ~+20us/layer).
template <bool RELU, bool CLS>
__global__ __launch_bounds__(256) void transform_mfma(
    const unsigned short* __restrict__ agg, const unsigned short* __restrict__ h,
    const unsigned short* __restrict__ wbuf, const float* __restrict__ bl,
    const float* __restrict__ Wout, const float* __restrict__ bout,
    unsigned short* __restrict__ out, float* __restrict__ out2, int N) {
    int t = threadIdx.x;
    int lane = t & 63;
    int w = t >> 6;
    int rq = lane & 15;
    int kg = lane >> 4;

    bf16x8 wf[16];
#pragma unroll
    for (int f = 0; f < 16; ++f)
        wf[f] = *(const bf16x8*)(wbuf + ((size_t)f * 64 + lane) * 8);
    float4 bias[4];
#pragma unroll
    for (int ot = 0; ot < 4; ++ot)
        bias[ot] = *(const float4*)(bl + ot * 16 + kg * 4);
    float4 wo0[4], wo1[4];
    float b0 = 0.f, b1 = 0.f;
    if (CLS) {
#pragma unroll
        for (int ot = 0; ot < 4; ++ot) {
            wo0[ot] = *(const float4*)(Wout + ot * 16 + kg * 4);
            wo1[ot] = *(const float4*)(Wout + D + ot * 16 + kg * 4);
        }
        b0 = bout[0]; b1 = bout[1];
    }

    int tiles = (N + 15) >> 4;
    for (int tile = blockIdx.x * 4 + w; tile < tiles; tile += gridDim.x * 4) {
        int r = tile * 16 + rq;
        int rc = min(r, N - 1);
        const unsigned short* ar = agg + (size_t)rc * D;
        const unsigned short* hr = h + (size_t)rc * D;
        bf16x8 d0 = *(const bf16x8*)(ar + kg * 8);
        bf16x8 d1 = *(const bf16x8*)(ar + 32 + kg * 8);
        bf16x8 d2 = *(const bf16x8*)(hr + kg * 8);
        bf16x8 d3 = *(const bf16x8*)(hr + 32 + kg * 8);

        f32x4 acc0 = {0.f, 0.f, 0.f, 0.f}, acc1 = acc0, acc2 = acc0, acc3 = acc0;
        acc0 = __builtin_amdgcn_mfma_f32_16x16x32_bf16(wf[0],  d0, acc0, 0, 0, 0);
        acc0 = __builtin_amdgcn_mfma_f32_16x16x32_bf16(wf[1],  d1, acc0, 0, 0, 0);
        acc0 = __builtin_amdgcn_mfma_f32_16x16x32_bf16(wf[2],  d2, acc0, 0, 0, 0);
        acc0 = __builtin_amdgcn_mfma_f32_16x16x32_bf16(wf[3],  d3, acc0, 0, 0, 0);
        acc1 = __builtin_amdgcn_mfma_f32_16x16x32_bf16(wf[4],  d0, acc1, 0, 0, 0);
        acc1 = __builtin_amdgcn_mfma_f32_16x16x32_bf16(wf[5],  d1, acc1, 0, 0, 0);
        acc1 = __builtin_amdgcn_mfma_f32_16x16x32_bf16(wf[6],  d2, acc1, 0, 0, 0);
        acc1 = __builtin_amdgcn_mfma_f32_16x16x32_bf16(wf[7],  d3, acc1, 0, 0, 0);
        acc2 = __builtin_amdgcn_mfma_f32_16x16x32_bf16(wf[8],  d0, acc2, 0, 0, 0);
        acc2 = __builtin_amdgcn_mfma_f32_16x16x32_bf16(wf[9],  d1, acc2, 0, 0, 0);
        acc2 = __builtin_amdgcn_mfma_f32_16x16x32_bf16(wf[10], d2, acc2, 0, 0, 0);
        acc2 = __builtin_amdgcn_mfma_f32_16x16x32_bf16(wf[11], d3, acc2, 0, 0, 0);
        acc3 = __builtin_amdgcn_mfma_f32_16x16x32_bf16(wf[12], d0, acc3, 0, 0, 0);
        acc3 = __builtin_amdgcn_mfma_f32_16x16x32_bf16(wf[13], d1, acc3, 0, 0, 0);
        acc3 = __builtin_amdgcn_mfma_f32_16x16x32_bf16(wf[14], d2, acc3, 0, 0, 0);
        acc3 = __builtin_amdgcn_mfma_f32_16x16x32_bf16(wf[15], d3, acc3, 0, 0, 0);

        f32x4 av[4] = {acc0, acc1, acc2, acc3};
        if (CLS) {
            float p0 = 0.f, p1 = 0.f;
#pragma unroll
            for (int ot = 0; ot < 4; ++ot) {
                float x0 = av[ot][0] + bias[ot].x;
                float x1 = av[ot][1] + bias[ot].y;
                float x2 = av[ot][2] + bias[ot].z;
                float x3 = av[ot][3] + bias[ot].w;
                p0 += x0 * wo0[ot].x + x1 * wo0[ot].y + x2 * wo0[ot].z + x3 * wo0[ot].w;
                p1 += x0 * wo1[ot].x + x1 * wo1[ot].y + x2 * wo1[ot].z + x3 * wo1[ot].w;
            }
            p0 += __shfl_xor(p0, 16); p1 += __shfl_xor(p1, 16);
            p0 += __shfl_xor(p0, 32); p1 += __shfl_xor(p1, 32);
            if (kg == 0 && r < N) {
                out2[(size_t)r * 2 + 0] = p0 + b0;
                out2[(size_t)r * 2 + 1] = p1 + b1;
            }
        } else if (r < N) {
            unsigned short* orow = out + (size_t)r * D + kg * 4;
#pragma unroll
            for (int ot = 0; ot < 4; ++ot) {
                float x0 = av[ot][0] + bias[ot].x;
                float x1 = av[ot][1] + bias[ot].y;
                float x2 = av[ot][2] + bias[ot].z;
                float x3 = av[ot][3] + bias[ot].w;
                if (RELU) {
                    x0 = fmaxf(x0, 0.f); x1 = fmaxf(x1, 0.f);
                    x2 = fmaxf(x2, 0.f); x3 = fmaxf(x3, 0.f);
                }
                uint2 o;
                o.x = (unsigned)f2bf(x0) | ((unsigned)f2bf(x1) << 16);
                o.y = (unsigned)f2bf(x2) | ((unsigned)f2bf(x3) << 16);
                *(uint2*)(orow + ot * 16) = o;
            }
        }
    }
}

extern "C" void kernel_launch(void* const* d_in, const int* in_sizes, int n_in,
                              void* d_out, int out_size, void* d_ws, size_t ws_size,
                              hipStream_t stream) {
    const float* x    = (const float*)d_in[0];
    const int*   ei   = (const int*)d_in[1];
    const float* Wl   = (const float*)d_in[2];
    const float* bl   = (const float*)d_in[3];
    const float* Wr   = (const float*)d_in[4];
    const float* Wout = (const float*)d_in[5];
    const float* bout = (const float*)d_in[6];
    float*       out  = (float*)d_out;

    const int N = in_sizes[0] / D;
    const int E = in_sizes[1] / 2;
    const int* src = ei;
    const int* dst = ei + E;
    const int NB = (N + 255) >> 8;  // <= NBMAX

    char* ws = (char*)d_ws;
    size_t off = 0;
    auto alloc = [&](size_t bytes) {
        char* p = ws + off;
        off = (off + bytes + 255) & ~(size_t)255;
        return p;
    };
    int*            bucketCursor = (int*)alloc((size_t)NB * 4);
    int*            rowStart     = (int*)alloc((size_t)N * 4);
    int*            rowDeg       = (int*)alloc((size_t)N * 4);
    int*            csr          = (int*)alloc((size_t)NB * CAP * 4);
    unsigned short* xb           = (unsigned short*)alloc((size_t)N * D * 2);
    unsigned short* hA           = (unsigned short*)alloc((size_t)N * D * 2);
    unsigned short* hB           = (unsigned short*)alloc((size_t)N * D * 2);
    unsigned short* aggB         = (unsigned short*)alloc((size_t)N * D * 2);
    unsigned short* wbuf         = (unsigned short*)alloc((size_t)3 * 16 * 64 * 8 * 2);
    // binned (NB*CAP*4 = 6.4MB) aliases hB (12.8MB): dead after csr_local, hB first written in layer 2
    unsigned*       binned       = (unsigned*)hB;

    // ---- prep (f2b zeroes bucketCursor -> no hipMemsetAsync anywhere) ----
    f2b_kernel<<<2048, 256, 0, stream>>>(x, xb, N * D / 4, bucketCursor, NB);
    wprep_kernel<<<48, 64, 0, stream>>>(Wl, Wr, wbuf);

    // ---- CSR build (2 kernels; fixed-capacity buckets, no global scan) ----
    bin_scatter<<<512, 256, 0, stream>>>(src, dst, bucketCursor, binned, E, NB);
    csr_local<<<NB, 256, 0, stream>>>(binned, bucketCursor, rowStart, rowDeg, csr, N, NB);

    const int WFRAG = 16 * 64 * 8;  // per-layer wbuf stride (ushorts)

    // ---- 3 layers (split kernels; grid-stride, proven r13 grids) ----
    aggregate_bf16<<<2048, 256, 0, stream>>>(xb, rowStart, rowDeg, csr, aggB, N);
    transform_mfma<true, false><<<1024, 256, 0, stream>>>(
        aggB, xb, wbuf, bl, nullptr, nullptr, hA, nullptr, N);

    aggregate_bf16<<<2048, 256, 0, stream>>>(hA, rowStart, rowDeg, csr, aggB, N);
    transform_mfma<true, false><<<1024, 256, 0, stream>>>(
        aggB, hA, wbuf + WFRAG, bl + D, nullptr, nullptr, hB, nullptr, N);

    aggregate_bf16<<<2048, 256, 0, stream>>>(hB, rowStart, rowDeg, csr, aggB, N);
    transform_mfma<false, true><<<1024, 256, 0, stream>>>(
        aggB, hB, wbuf + 2 * WFRAG, bl + 2 * D, Wout, bout, nullptr, out, N);
}